// Round 1
// baseline (1231.195 us; speedup 1.0000x reference)
//
#include <hip/hip_runtime.h>
#include <math.h>

#define D_IN 16
#define D    64
#define H    128
#define EPSL 1e-5f

// ---------------- quad (4-lane) sum via DPP quad_perm — VALU only -------------
__device__ __forceinline__ float qsum(float v)
{
    float t = __int_as_float(__builtin_amdgcn_update_dpp(
        0, __float_as_int(v), 0xB1, 0xF, 0xF, true));   // quad_perm [1,0,3,2]
    v += t;
    t = __int_as_float(__builtin_amdgcn_update_dpp(
        0, __float_as_int(v), 0x4E, 0xF, 0xF, true));   // quad_perm [2,3,0,1]
    return v + t;
}

// ---------------- weight transpose (once per launch) ----------------
// w0t[j][k] = w0[k][j]   (64 x 16)
// wat[l][j2][k] = wa[l][k][j2]  (L x 128 x 64)
__global__ void k_transpose_w(const float* __restrict__ w0,
                              const float* __restrict__ wa,
                              float* __restrict__ w0t,
                              float* __restrict__ wat, int L)
{
    int i = blockIdx.x * blockDim.x + threadIdx.x;
    if (i < D * D_IN) {
        int j = i / D_IN, k = i % D_IN;
        w0t[i] = w0[k * D + j];
    }
    int tot = L * H * D;
    for (int t = i; t < tot; t += gridDim.x * blockDim.x) {
        int l  = t / (H * D);
        int r  = t % (H * D);
        int j2 = r / D, k = r % D;
        wat[l * H * D + j2 * D + k] = wa[l * D * H + k * H + j2];
    }
}

__global__ void k_zero(int* __restrict__ p, int n)
{
    int i = blockIdx.x * blockDim.x + threadIdx.x;
    if (i < n) p[i] = 0;
}

__global__ void k_hist(const int* __restrict__ dst, int* __restrict__ cnt, int E)
{
    int i = blockIdx.x * blockDim.x + threadIdx.x;
    if (i < E) atomicAdd(&cnt[dst[i]], 1);
}

// ---------------- hierarchical exclusive scan (3 kernels) ---------------------
// off[g+1] = inclusive block scan; bsum[b] = block total
__global__ void k_scan_blk(const int* __restrict__ cnt, int* __restrict__ off,
                           int* __restrict__ bsum, int N)
{
    __shared__ int sm[256];
    int t = threadIdx.x;
    int g = blockIdx.x * 256 + t;
    int v = (g < N) ? cnt[g] : 0;
    sm[t] = v;
    __syncthreads();
    for (int d2 = 1; d2 < 256; d2 <<= 1) {
        int u = (t >= d2) ? sm[t - d2] : 0;
        __syncthreads();
        sm[t] += u;
        __syncthreads();
    }
    if (g < N) off[g + 1] = sm[t];
    if (t == 255) bsum[blockIdx.x] = sm[255];
}

// exclusive scan of block sums (G <= 1024)
__global__ void k_scan_top(int* __restrict__ bsum, int G)
{
    __shared__ int sm[1024];
    int t = threadIdx.x;
    int v = (t < G) ? bsum[t] : 0;
    sm[t] = v;
    __syncthreads();
    for (int d2 = 1; d2 < 1024; d2 <<= 1) {
        int u = (t >= d2) ? sm[t - d2] : 0;
        __syncthreads();
        sm[t] += u;
        __syncthreads();
    }
    if (t < G) bsum[t] = sm[t] - v;   // exclusive
}

__global__ void k_scan_add(int* __restrict__ off, const int* __restrict__ bsum, int N)
{
    int g = blockIdx.x * 256 + threadIdx.x;
    if (g < N) off[g + 1] += bsum[blockIdx.x];
    if (g == 0) off[0] = 0;
}

__global__ void k_fill(const int* __restrict__ src, const int* __restrict__ dst,
                       const int* __restrict__ off, int* __restrict__ fill,
                       int* __restrict__ csr, int E)
{
    int i = blockIdx.x * blockDim.x + threadIdx.x;
    if (i < E) {
        int d = dst[i];
        int p = atomicAdd(&fill[d], 1);
        csr[off[d] + p] = src[i];
    }
}

// ---------------- fused per-layer MLP: m = mlp_silu_ln(h; wa,ba,wb,bb) --------
// Quad-cooperative: 4 lanes per node. Lane c holds h[node][c*16..+16) in regs.
// Per hidden unit j2: partial 16-dot -> DPP quad-sum -> relu -> rank-1 update
// of the lane's 16 output channels. No LDS, no barriers, no scalarized weight
// streams: all weight reads are vector loads (vmcnt pipeline, L1 broadcast).
__global__ __launch_bounds__(256) void k_mlp(const float* __restrict__ h,
                                             const float* __restrict__ wat,
                                             const float* __restrict__ ba,
                                             const float* __restrict__ wb,
                                             const float* __restrict__ bb,
                                             float* __restrict__ m, int N)
{
    int tid  = threadIdx.x;
    int c    = tid & 3;           // quad lane -> 16-wide slice
    int nl   = tid >> 2;          // node within block [0..63]
    int node = blockIdx.x * 64 + nl;
    int nc   = min(node, N - 1);

    const float4* hp = (const float4*)(h + (size_t)nc * D + c * 16);
    float4 h0 = hp[0], h1 = hp[1], h2 = hp[2], h3 = hp[3];

    const float4* bbp = (const float4*)(bb + c * 16);
    float4 a0 = bbp[0], a1 = bbp[1], a2 = bbp[2], a3 = bbp[3];

#pragma unroll 4
    for (int j2 = 0; j2 < H; ++j2) {
        const float4* wr = (const float4*)(wat + j2 * D + c * 16);
        float4 w0 = wr[0], w1 = wr[1], w2 = wr[2], w3 = wr[3];
        float p0 = fmaf(h0.x, w0.x, fmaf(h0.y, w0.y, fmaf(h0.z, w0.z, h0.w * w0.w)));
        float p1 = fmaf(h1.x, w1.x, fmaf(h1.y, w1.y, fmaf(h1.z, w1.z, h1.w * w1.w)));
        float p2 = fmaf(h2.x, w2.x, fmaf(h2.y, w2.y, fmaf(h2.z, w2.z, h2.w * w2.w)));
        float p3 = fmaf(h3.x, w3.x, fmaf(h3.y, w3.y, fmaf(h3.z, w3.z, h3.w * w3.w)));
        float hd = qsum((p0 + p1) + (p2 + p3)) + ba[j2];
        hd = fmaxf(hd, 0.f);

        const float4* wo = (const float4*)(wb + j2 * D + c * 16);
        float4 v0 = wo[0], v1 = wo[1], v2 = wo[2], v3 = wo[3];
        a0.x = fmaf(hd, v0.x, a0.x); a0.y = fmaf(hd, v0.y, a0.y);
        a0.z = fmaf(hd, v0.z, a0.z); a0.w = fmaf(hd, v0.w, a0.w);
        a1.x = fmaf(hd, v1.x, a1.x); a1.y = fmaf(hd, v1.y, a1.y);
        a1.z = fmaf(hd, v1.z, a1.z); a1.w = fmaf(hd, v1.w, a1.w);
        a2.x = fmaf(hd, v2.x, a2.x); a2.y = fmaf(hd, v2.y, a2.y);
        a2.z = fmaf(hd, v2.z, a2.z); a2.w = fmaf(hd, v2.w, a2.w);
        a3.x = fmaf(hd, v3.x, a3.x); a3.y = fmaf(hd, v3.y, a3.y);
        a3.z = fmaf(hd, v3.z, a3.z); a3.w = fmaf(hd, v3.w, a3.w);
    }

    // SiLU
#define SILU4(v) { v.x = v.x / (1.f + __expf(-v.x)); v.y = v.y / (1.f + __expf(-v.y)); \
                   v.z = v.z / (1.f + __expf(-v.z)); v.w = v.w / (1.f + __expf(-v.w)); }
    SILU4(a0) SILU4(a1) SILU4(a2) SILU4(a3)
#undef SILU4

    // LN across 64 channels = quad reduction of per-lane 16-sums
    float s = (a0.x + a0.y + a0.z + a0.w) + (a1.x + a1.y + a1.z + a1.w)
            + (a2.x + a2.y + a2.z + a2.w) + (a3.x + a3.y + a3.z + a3.w);
    float q = 0.f;
#define SQ4(v) q = fmaf(v.x, v.x, fmaf(v.y, v.y, fmaf(v.z, v.z, fmaf(v.w, v.w, q))));
    SQ4(a0) SQ4(a1) SQ4(a2) SQ4(a3)
#undef SQ4
    float ts = qsum(s), tq = qsum(q);
    float mu  = ts * (1.f / D);
    float var = tq * (1.f / D) - mu * mu;
    float inv = rsqrtf(var + EPSL);

    if (node < N) {
        float4* mp = (float4*)(m + (size_t)node * D + c * 16);
        float4 v;
        v.x = (a0.x - mu) * inv; v.y = (a0.y - mu) * inv;
        v.z = (a0.z - mu) * inv; v.w = (a0.w - mu) * inv; mp[0] = v;
        v.x = (a1.x - mu) * inv; v.y = (a1.y - mu) * inv;
        v.z = (a1.z - mu) * inv; v.w = (a1.w - mu) * inv; mp[1] = v;
        v.x = (a2.x - mu) * inv; v.y = (a2.y - mu) * inv;
        v.z = (a2.z - mu) * inv; v.w = (a2.w - mu) * inv; mp[2] = v;
        v.x = (a3.x - mu) * inv; v.y = (a3.y - mu) * inv;
        v.z = (a3.z - mu) * inv; v.w = (a3.w - mu) * inv; mp[3] = v;
    }
}

// ---------------- fused initial embedding: h = mlp_silu_ln(x; w0,b0,w1,b1) ----
// Same quad structure; D_IN=16 -> one float4 of x per lane.
__global__ __launch_bounds__(256) void k_init(const float* __restrict__ x,
                                              const float* __restrict__ w0t,
                                              const float* __restrict__ b0,
                                              const float* __restrict__ w1,
                                              const float* __restrict__ b1,
                                              float* __restrict__ h, int N)
{
    int tid  = threadIdx.x;
    int c    = tid & 3;
    int nl   = tid >> 2;
    int node = blockIdx.x * 64 + nl;
    int nc   = min(node, N - 1);

    float4 xv = ((const float4*)(x + (size_t)nc * D_IN))[c];

    const float4* b1p = (const float4*)(b1 + c * 16);
    float4 a0 = b1p[0], a1 = b1p[1], a2 = b1p[2], a3 = b1p[3];

#pragma unroll 4
    for (int j = 0; j < D; ++j) {
        float4 w = ((const float4*)(w0t + j * D_IN))[c];
        float p  = fmaf(xv.x, w.x, fmaf(xv.y, w.y, fmaf(xv.z, w.z, xv.w * w.w)));
        float hd = qsum(p) + b0[j];
        hd = fmaxf(hd, 0.f);

        const float4* wo = (const float4*)(w1 + j * D + c * 16);
        float4 v0 = wo[0], v1 = wo[1], v2 = wo[2], v3 = wo[3];
        a0.x = fmaf(hd, v0.x, a0.x); a0.y = fmaf(hd, v0.y, a0.y);
        a0.z = fmaf(hd, v0.z, a0.z); a0.w = fmaf(hd, v0.w, a0.w);
        a1.x = fmaf(hd, v1.x, a1.x); a1.y = fmaf(hd, v1.y, a1.y);
        a1.z = fmaf(hd, v1.z, a1.z); a1.w = fmaf(hd, v1.w, a1.w);
        a2.x = fmaf(hd, v2.x, a2.x); a2.y = fmaf(hd, v2.y, a2.y);
        a2.z = fmaf(hd, v2.z, a2.z); a2.w = fmaf(hd, v2.w, a2.w);
        a3.x = fmaf(hd, v3.x, a3.x); a3.y = fmaf(hd, v3.y, a3.y);
        a3.z = fmaf(hd, v3.z, a3.z); a3.w = fmaf(hd, v3.w, a3.w);
    }

#define SILU4(v) { v.x = v.x / (1.f + __expf(-v.x)); v.y = v.y / (1.f + __expf(-v.y)); \
                   v.z = v.z / (1.f + __expf(-v.z)); v.w = v.w / (1.f + __expf(-v.w)); }
    SILU4(a0) SILU4(a1) SILU4(a2) SILU4(a3)
#undef SILU4

    float s = (a0.x + a0.y + a0.z + a0.w) + (a1.x + a1.y + a1.z + a1.w)
            + (a2.x + a2.y + a2.z + a2.w) + (a3.x + a3.y + a3.z + a3.w);
    float q = 0.f;
#define SQ4(v) q = fmaf(v.x, v.x, fmaf(v.y, v.y, fmaf(v.z, v.z, fmaf(v.w, v.w, q))));
    SQ4(a0) SQ4(a1) SQ4(a2) SQ4(a3)
#undef SQ4
    float ts = qsum(s), tq = qsum(q);
    float mu  = ts * (1.f / D);
    float var = tq * (1.f / D) - mu * mu;
    float inv = rsqrtf(var + EPSL);

    if (node < N) {
        float4* hp2 = (float4*)(h + (size_t)node * D + c * 16);
        float4 v;
        v.x = (a0.x - mu) * inv; v.y = (a0.y - mu) * inv;
        v.z = (a0.z - mu) * inv; v.w = (a0.w - mu) * inv; hp2[0] = v;
        v.x = (a1.x - mu) * inv; v.y = (a1.y - mu) * inv;
        v.z = (a1.z - mu) * inv; v.w = (a1.w - mu) * inv; hp2[1] = v;
        v.x = (a2.x - mu) * inv; v.y = (a2.y - mu) * inv;
        v.z = (a2.z - mu) * inv; v.w = (a2.w - mu) * inv; hp2[2] = v;
        v.x = (a3.x - mu) * inv; v.y = (a3.y - mu) * inv;
        v.z = (a3.z - mu) * inv; v.w = (a3.w - mu) * inv; hp2[3] = v;
    }
}

// ---------------- aggregation: h += segment_mean(m[src], dst) ------------------
// 16 lanes per node, float4 per lane
__global__ __launch_bounds__(256) void k_agg(const float* __restrict__ m,
                                             const int* __restrict__ csr,
                                             const int* __restrict__ off,
                                             const int* __restrict__ cnt,
                                             float* __restrict__ h, int N)
{
    int g = threadIdx.x >> 4;
    int c = threadIdx.x & 15;
    int node = blockIdx.x * 16 + g;
    if (node >= N) return;

    int b  = off[node];
    int e2 = off[node + 1];
    float4 s = {0.f, 0.f, 0.f, 0.f};
    for (int e = b; e < e2; ++e) {
        int sn = csr[e];
        float4 v = ((const float4*)(m + (size_t)sn * D))[c];
        s.x += v.x; s.y += v.y; s.z += v.z; s.w += v.w;
    }
    float dnm = fmaxf((float)cnt[node], 1.f);
    float inv = 1.f / dnm;

    float4* hp = (float4*)(h + (size_t)node * D);
    float4 hv = hp[c];
    hv.x = fmaf(s.x, inv, hv.x);
    hv.y = fmaf(s.y, inv, hv.y);
    hv.z = fmaf(s.z, inv, hv.z);
    hv.w = fmaf(s.w, inv, hv.w);
    hp[c] = hv;
}

extern "C" void kernel_launch(void* const* d_in, const int* in_sizes, int n_in,
                              void* d_out, int out_size, void* d_ws, size_t ws_size,
                              hipStream_t stream)
{
    const float* x  = (const float*)d_in[0];
    const int*   ei = (const int*)d_in[1];
    const float* w0 = (const float*)d_in[2];
    const float* b0 = (const float*)d_in[3];
    const float* w1 = (const float*)d_in[4];
    const float* b1 = (const float*)d_in[5];
    const float* wa = (const float*)d_in[6];
    const float* ba = (const float*)d_in[7];
    const float* wb = (const float*)d_in[8];
    const float* bb = (const float*)d_in[9];

    const int N = in_sizes[0] / D_IN;
    const int E = in_sizes[1] / 2;
    const int L = in_sizes[6] / (D * H);

    const int* src = ei;
    const int* dst = ei + E;

    // workspace layout (256B aligned chunks)
    char* ws = (char*)d_ws;
    size_t o = 0;
    auto carve = [&](size_t bytes) -> char* {
        char* p = ws + o;
        o = (o + bytes + 255) & ~(size_t)255;
        return p;
    };
    float* m    = (float*)carve((size_t)N * D * sizeof(float));
    int*   csr  = (int*)  carve((size_t)E * sizeof(int));
    int*   cnt  = (int*)  carve((size_t)N * sizeof(int));
    int*   fill = (int*)  carve((size_t)N * sizeof(int));
    int*   offp = (int*)  carve((size_t)(N + 1) * sizeof(int));
    int*   bsum = (int*)  carve((size_t)1024 * sizeof(int));
    float* w0t  = (float*)carve((size_t)D * D_IN * sizeof(float));
    float* wat  = (float*)carve((size_t)L * H * D * sizeof(float));

    float* h = (float*)d_out;

    const int nb = (N + 63) / 64;
    const int G1 = (N + 255) / 256;

    k_transpose_w<<<64, 256, 0, stream>>>(w0, wa, w0t, wat, L);
    k_zero<<<(N + 255) / 256, 256, 0, stream>>>(cnt, N);
    k_zero<<<(N + 255) / 256, 256, 0, stream>>>(fill, N);
    k_hist<<<(E + 255) / 256, 256, 0, stream>>>(dst, cnt, E);
    k_scan_blk<<<G1, 256, 0, stream>>>(cnt, offp, bsum, N);
    k_scan_top<<<1, 1024, 0, stream>>>(bsum, G1);
    k_scan_add<<<G1, 256, 0, stream>>>(offp, bsum, N);
    k_fill<<<(E + 255) / 256, 256, 0, stream>>>(src, dst, offp, fill, csr, E);

    k_init<<<nb, 256, 0, stream>>>(x, w0t, b0, w1, b1, h, N);

    for (int l = 0; l < L; ++l) {
        k_mlp<<<nb, 256, 0, stream>>>(h, wat + (size_t)l * H * D,
                                      ba + (size_t)l * H,
                                      wb + (size_t)l * H * D,
                                      bb + (size_t)l * D, m, N);
        k_agg<<<(N + 15) / 16, 256, 0, stream>>>(m, csr, offp, cnt, h, N);
    }
}

// Round 2
// 575.645 us; speedup vs baseline: 2.1388x; 2.1388x over previous
//
#include <hip/hip_runtime.h>
#include <math.h>

#define D_IN 16
#define D    64
#define H    128
#define EPSL 1e-5f
#define TN   64    // nodes per block (MLP kernels)

#define FOR4(M)  M(0) M(1) M(2) M(3)
#define FOR16(M) M(0) M(1) M(2) M(3) M(4) M(5) M(6) M(7) \
                 M(8) M(9) M(10) M(11) M(12) M(13) M(14) M(15)

// ---- 16-float LDS store / accumulate (b32, conflict-free at stride 65) ------
__device__ __forceinline__ void st16(float* p,
    const float4 a, const float4 b, const float4 c, const float4 d)
{
    p[0]=a.x;  p[1]=a.y;  p[2]=a.z;  p[3]=a.w;
    p[4]=b.x;  p[5]=b.y;  p[6]=b.z;  p[7]=b.w;
    p[8]=c.x;  p[9]=c.y;  p[10]=c.z; p[11]=c.w;
    p[12]=d.x; p[13]=d.y; p[14]=d.z; p[15]=d.w;
}
__device__ __forceinline__ void add16(float* p,
    const float4 a, const float4 b, const float4 c, const float4 d)
{
    p[0]+=a.x;  p[1]+=a.y;  p[2]+=a.z;  p[3]+=a.w;
    p[4]+=b.x;  p[5]+=b.y;  p[6]+=b.z;  p[7]+=b.w;
    p[8]+=c.x;  p[9]+=c.y;  p[10]+=c.z; p[11]+=c.w;
    p[12]+=d.x; p[13]+=d.y; p[14]+=d.z; p[15]+=d.w;
}

// ---------------- weight transpose (once per launch) ----------------
// w0t[j][k] = w0[k][j]   (64 x 16)
// wat[l][j2][k] = wa[l][k][j2]  (L x 128 x 64)
__global__ void k_transpose_w(const float* __restrict__ w0,
                              const float* __restrict__ wa,
                              float* __restrict__ w0t,
                              float* __restrict__ wat, int L)
{
    int i = blockIdx.x * blockDim.x + threadIdx.x;
    if (i < D * D_IN) {
        int j = i / D_IN, k = i % D_IN;
        w0t[i] = w0[k * D + j];
    }
    int tot = L * H * D;
    for (int t = i; t < tot; t += gridDim.x * blockDim.x) {
        int l  = t / (H * D);
        int r  = t % (H * D);
        int j2 = r / D, k = r % D;
        wat[l * H * D + j2 * D + k] = wa[l * D * H + k * H + j2];
    }
}

__global__ void k_zero(int* __restrict__ p, int n)
{
    int i = blockIdx.x * blockDim.x + threadIdx.x;
    if (i < n) p[i] = 0;
}

__global__ void k_hist(const int* __restrict__ dst, int* __restrict__ cnt, int E)
{
    int i = blockIdx.x * blockDim.x + threadIdx.x;
    if (i < E) atomicAdd(&cnt[dst[i]], 1);
}

// ---------------- hierarchical exclusive scan (3 kernels) ---------------------
__global__ void k_scan_blk(const int* __restrict__ cnt, int* __restrict__ off,
                           int* __restrict__ bsum, int N)
{
    __shared__ int sm[256];
    int t = threadIdx.x;
    int g = blockIdx.x * 256 + t;
    int v = (g < N) ? cnt[g] : 0;
    sm[t] = v;
    __syncthreads();
    for (int d2 = 1; d2 < 256; d2 <<= 1) {
        int u = (t >= d2) ? sm[t - d2] : 0;
        __syncthreads();
        sm[t] += u;
        __syncthreads();
    }
    if (g < N) off[g + 1] = sm[t];
    if (t == 255) bsum[blockIdx.x] = sm[255];
}

__global__ void k_scan_top(int* __restrict__ bsum, int G)
{
    __shared__ int sm[1024];
    int t = threadIdx.x;
    int v = (t < G) ? bsum[t] : 0;
    sm[t] = v;
    __syncthreads();
    for (int d2 = 1; d2 < 1024; d2 <<= 1) {
        int u = (t >= d2) ? sm[t - d2] : 0;
        __syncthreads();
        sm[t] += u;
        __syncthreads();
    }
    if (t < G) bsum[t] = sm[t] - v;   // exclusive
}

__global__ void k_scan_add(int* __restrict__ off, const int* __restrict__ bsum, int N)
{
    int g = blockIdx.x * 256 + threadIdx.x;
    if (g < N) off[g + 1] += bsum[blockIdx.x];
    if (g == 0) off[0] = 0;
}

__global__ void k_fill(const int* __restrict__ src, const int* __restrict__ dst,
                       const int* __restrict__ off, int* __restrict__ fill,
                       int* __restrict__ csr, int E)
{
    int i = blockIdx.x * blockDim.x + threadIdx.x;
    if (i < E) {
        int d = dst[i];
        int p = atomicAdd(&fill[d], 1);
        csr[off[d] + p] = src[i];
    }
}

// ---------------- per-layer MLP: m = mlp_silu_ln(h; wa,ba,wb,bb) --------------
// K-split: thread (split,nloc) keeps hid[split*32..+32) of its node in REGS
// (phase 1), then accumulates partials for ALL 64 output channels over those
// 32 hiddens (phase 2: 64 FMA per wave-uniform 256B s_load row, no ds_read).
// Cross-split reduce: 4-pass channel-quarter rotation in LDS (conflict-free
// b32, all waves active, disjoint regions per pass). Then bias+SiLU+LN.
__global__ __launch_bounds__(256, 4) void k_mlp(const float* __restrict__ h,
                                                const float* __restrict__ wat,
                                                const float* __restrict__ ba,
                                                const float* __restrict__ wb,
                                                const float* __restrict__ bb,
                                                float* __restrict__ m, int N)
{
    __shared__ float buf[TN * 65];     // 16.25 KB channel-sum rotation buffer
    __shared__ float red_s[256];
    __shared__ float red_q[256];

    int tid   = threadIdx.x;
    int nloc  = tid & 63;
    int split = __builtin_amdgcn_readfirstlane(tid >> 6);   // wave id, uniform
    int node  = blockIdx.x * TN + nloc;
    int nc    = min(node, N - 1);

    const float4* hp = (const float4*)(h + (size_t)nc * D);
#define LOADH(i) float4 h##i = hp[i];
    FOR16(LOADH)
#undef LOADH

    // phase 1: hid[jj] for j2 = split*32 + jj, kept in registers
    float hv[32];
#pragma unroll
    for (int jj = 0; jj < 32; ++jj) {
        int j2 = split * 32 + jj;
        const float4* wr_ = (const float4*)(wat + j2 * D);
        float p0 = 0.f, p1 = 0.f, p2 = 0.f, p3 = 0.f;
#define DOT1(i) { float4 w_ = wr_[i]; \
        p0 = fmaf(h##i.x, w_.x, p0); p1 = fmaf(h##i.y, w_.y, p1); \
        p2 = fmaf(h##i.z, w_.z, p2); p3 = fmaf(h##i.w, w_.w, p3); }
        FOR16(DOT1)
#undef DOT1
        hv[jj] = fmaxf(ba[j2] + ((p0 + p1) + (p2 + p3)), 0.f);
    }

    // phase 2: partials for all 64 channels over my 32 hiddens
    float4 a0={0,0,0,0}, a1={0,0,0,0}, a2={0,0,0,0}, a3={0,0,0,0};
    float4 a4={0,0,0,0}, a5={0,0,0,0}, a6={0,0,0,0}, a7={0,0,0,0};
    float4 a8={0,0,0,0}, a9={0,0,0,0}, a10={0,0,0,0}, a11={0,0,0,0};
    float4 a12={0,0,0,0}, a13={0,0,0,0}, a14={0,0,0,0}, a15={0,0,0,0};
#pragma unroll
    for (int jj = 0; jj < 32; ++jj) {
        int j2 = split * 32 + jj;
        const float4* wo_ = (const float4*)(wb + j2 * D);
        float hd_ = hv[jj];
#define ACC1(i) { float4 w_ = wo_[i]; \
        a##i.x = fmaf(hd_, w_.x, a##i.x); a##i.y = fmaf(hd_, w_.y, a##i.y); \
        a##i.z = fmaf(hd_, w_.z, a##i.z); a##i.w = fmaf(hd_, w_.w, a##i.w); }
        FOR16(ACC1)
#undef ACC1
    }

    // cross-split reduce: rotation over channel quarters (disjoint per pass)
    float* bp = buf + nloc * 65;
#pragma unroll
    for (int p = 0; p < 4; ++p) {
        int q = (split + p) & 3;
        float* qp = bp + q * 16;
        if (p == 0) {
            switch (q) {
                case 0:  st16(qp, a0,  a1,  a2,  a3);  break;
                case 1:  st16(qp, a4,  a5,  a6,  a7);  break;
                case 2:  st16(qp, a8,  a9,  a10, a11); break;
                default: st16(qp, a12, a13, a14, a15); break;
            }
        } else {
            switch (q) {
                case 0:  add16(qp, a0,  a1,  a2,  a3);  break;
                case 1:  add16(qp, a4,  a5,  a6,  a7);  break;
                case 2:  add16(qp, a8,  a9,  a10, a11); break;
                default: add16(qp, a12, a13, a14, a15); break;
            }
        }
        __syncthreads();
    }

    // readback my 16 channels, + bias, SiLU
    float* rp = bp + split * 16;
    float4 o0, o1, o2, o3;
    o0.x=rp[0];  o0.y=rp[1];  o0.z=rp[2];  o0.w=rp[3];
    o1.x=rp[4];  o1.y=rp[5];  o1.z=rp[6];  o1.w=rp[7];
    o2.x=rp[8];  o2.y=rp[9];  o2.z=rp[10]; o2.w=rp[11];
    o3.x=rp[12]; o3.y=rp[13]; o3.z=rp[14]; o3.w=rp[15];
    const float4* bq = (const float4*)(bb + split * 16);
    float4 bv0=bq[0], bv1=bq[1], bv2=bq[2], bv3=bq[3];
    o0.x+=bv0.x; o0.y+=bv0.y; o0.z+=bv0.z; o0.w+=bv0.w;
    o1.x+=bv1.x; o1.y+=bv1.y; o1.z+=bv1.z; o1.w+=bv1.w;
    o2.x+=bv2.x; o2.y+=bv2.y; o2.z+=bv2.z; o2.w+=bv2.w;
    o3.x+=bv3.x; o3.y+=bv3.y; o3.z+=bv3.z; o3.w+=bv3.w;

#define SILU4(v) { v.x = v.x / (1.f + __expf(-v.x)); v.y = v.y / (1.f + __expf(-v.y)); \
                   v.z = v.z / (1.f + __expf(-v.z)); v.w = v.w / (1.f + __expf(-v.w)); }
    SILU4(o0) SILU4(o1) SILU4(o2) SILU4(o3)
#undef SILU4

    // LN across 64 channels: 4-way cross-wave reduce
    float s = (o0.x + o0.y + o0.z + o0.w) + (o1.x + o1.y + o1.z + o1.w)
            + (o2.x + o2.y + o2.z + o2.w) + (o3.x + o3.y + o3.z + o3.w);
    float qv = 0.f;
#define SQ4(v) qv = fmaf(v.x, v.x, fmaf(v.y, v.y, fmaf(v.z, v.z, fmaf(v.w, v.w, qv))));
    SQ4(o0) SQ4(o1) SQ4(o2) SQ4(o3)
#undef SQ4
    red_s[tid] = s;
    red_q[tid] = qv;
    __syncthreads();

    float ts = 0.f, tq = 0.f;
#pragma unroll
    for (int sp = 0; sp < 4; ++sp) {
        ts += red_s[sp * 64 + nloc];
        tq += red_q[sp * 64 + nloc];
    }
    float mu  = ts * (1.f / D);
    float var = tq * (1.f / D) - mu * mu;
    float inv = rsqrtf(var + EPSL);

    if (node < N) {
        float4* mp = (float4*)(m + (size_t)node * D + split * 16);
        float4 v;
        v.x = (o0.x - mu) * inv; v.y = (o0.y - mu) * inv;
        v.z = (o0.z - mu) * inv; v.w = (o0.w - mu) * inv; mp[0] = v;
        v.x = (o1.x - mu) * inv; v.y = (o1.y - mu) * inv;
        v.z = (o1.z - mu) * inv; v.w = (o1.w - mu) * inv; mp[1] = v;
        v.x = (o2.x - mu) * inv; v.y = (o2.y - mu) * inv;
        v.z = (o2.z - mu) * inv; v.w = (o2.w - mu) * inv; mp[2] = v;
        v.x = (o3.x - mu) * inv; v.y = (o3.y - mu) * inv;
        v.z = (o3.z - mu) * inv; v.w = (o3.w - mu) * inv; mp[3] = v;
    }
}

// ---------------- initial embedding: h = mlp_silu_ln(x; w0,b0,w1,b1) ----------
// same K-split structure; hidden dim 64 -> 16 hidden units per thread
__global__ __launch_bounds__(256, 4) void k_init(const float* __restrict__ x,
                                                 const float* __restrict__ w0t,
                                                 const float* __restrict__ b0,
                                                 const float* __restrict__ w1,
                                                 const float* __restrict__ b1,
                                                 float* __restrict__ h, int N)
{
    __shared__ float buf[TN * 65];
    __shared__ float red_s[256];
    __shared__ float red_q[256];

    int tid   = threadIdx.x;
    int nloc  = tid & 63;
    int split = __builtin_amdgcn_readfirstlane(tid >> 6);
    int node  = blockIdx.x * TN + nloc;
    int nc    = min(node, N - 1);

    const float4* xp = (const float4*)(x + (size_t)nc * D_IN);
#define LOADX(i) float4 x##i = xp[i];
    FOR4(LOADX)
#undef LOADX

    // phase 1: hid[jj] for j = split*16 + jj
    float hv[16];
#pragma unroll
    for (int jj = 0; jj < 16; ++jj) {
        int j = split * 16 + jj;
        const float4* wr_ = (const float4*)(w0t + j * D_IN);
        float p0 = 0.f, p1 = 0.f, p2 = 0.f, p3 = 0.f;
#define DOT1(i) { float4 w_ = wr_[i]; \
        p0 = fmaf(x##i.x, w_.x, p0); p1 = fmaf(x##i.y, w_.y, p1); \
        p2 = fmaf(x##i.z, w_.z, p2); p3 = fmaf(x##i.w, w_.w, p3); }
        FOR4(DOT1)
#undef DOT1
        hv[jj] = fmaxf(b0[j] + ((p0 + p1) + (p2 + p3)), 0.f);
    }

    // phase 2: partials for all 64 channels over my 16 hiddens
    float4 a0={0,0,0,0}, a1={0,0,0,0}, a2={0,0,0,0}, a3={0,0,0,0};
    float4 a4={0,0,0,0}, a5={0,0,0,0}, a6={0,0,0,0}, a7={0,0,0,0};
    float4 a8={0,0,0,0}, a9={0,0,0,0}, a10={0,0,0,0}, a11={0,0,0,0};
    float4 a12={0,0,0,0}, a13={0,0,0,0}, a14={0,0,0,0}, a15={0,0,0,0};
#pragma unroll
    for (int jj = 0; jj < 16; ++jj) {
        int j = split * 16 + jj;
        const float4* wo_ = (const float4*)(w1 + j * D);
        float hd_ = hv[jj];
#define ACC1(i) { float4 w_ = wo_[i]; \
        a##i.x = fmaf(hd_, w_.x, a##i.x); a##i.y = fmaf(hd_, w_.y, a##i.y); \
        a##i.z = fmaf(hd_, w_.z, a##i.z); a##i.w = fmaf(hd_, w_.w, a##i.w); }
        FOR16(ACC1)
#undef ACC1
    }

    float* bp = buf + nloc * 65;
#pragma unroll
    for (int p = 0; p < 4; ++p) {
        int q = (split + p) & 3;
        float* qp = bp + q * 16;
        if (p == 0) {
            switch (q) {
                case 0:  st16(qp, a0,  a1,  a2,  a3);  break;
                case 1:  st16(qp, a4,  a5,  a6,  a7);  break;
                case 2:  st16(qp, a8,  a9,  a10, a11); break;
                default: st16(qp, a12, a13, a14, a15); break;
            }
        } else {
            switch (q) {
                case 0:  add16(qp, a0,  a1,  a2,  a3);  break;
                case 1:  add16(qp, a4,  a5,  a6,  a7);  break;
                case 2:  add16(qp, a8,  a9,  a10, a11); break;
                default: add16(qp, a12, a13, a14, a15); break;
            }
        }
        __syncthreads();
    }

    float* rp = bp + split * 16;
    float4 o0, o1, o2, o3;
    o0.x=rp[0];  o0.y=rp[1];  o0.z=rp[2];  o0.w=rp[3];
    o1.x=rp[4];  o1.y=rp[5];  o1.z=rp[6];  o1.w=rp[7];
    o2.x=rp[8];  o2.y=rp[9];  o2.z=rp[10]; o2.w=rp[11];
    o3.x=rp[12]; o3.y=rp[13]; o3.z=rp[14]; o3.w=rp[15];
    const float4* bq = (const float4*)(b1 + split * 16);
    float4 bv0=bq[0], bv1=bq[1], bv2=bq[2], bv3=bq[3];
    o0.x+=bv0.x; o0.y+=bv0.y; o0.z+=bv0.z; o0.w+=bv0.w;
    o1.x+=bv1.x; o1.y+=bv1.y; o1.z+=bv1.z; o1.w+=bv1.w;
    o2.x+=bv2.x; o2.y+=bv2.y; o2.z+=bv2.z; o2.w+=bv2.w;
    o3.x+=bv3.x; o3.y+=bv3.y; o3.z+=bv3.z; o3.w+=bv3.w;

#define SILU4(v) { v.x = v.x / (1.f + __expf(-v.x)); v.y = v.y / (1.f + __expf(-v.y)); \
                   v.z = v.z / (1.f + __expf(-v.z)); v.w = v.w / (1.f + __expf(-v.w)); }
    SILU4(o0) SILU4(o1) SILU4(o2) SILU4(o3)
#undef SILU4

    float s = (o0.x + o0.y + o0.z + o0.w) + (o1.x + o1.y + o1.z + o1.w)
            + (o2.x + o2.y + o2.z + o2.w) + (o3.x + o3.y + o3.z + o3.w);
    float qv = 0.f;
#define SQ4(v) qv = fmaf(v.x, v.x, fmaf(v.y, v.y, fmaf(v.z, v.z, fmaf(v.w, v.w, qv))));
    SQ4(o0) SQ4(o1) SQ4(o2) SQ4(o3)
#undef SQ4
    red_s[tid] = s;
    red_q[tid] = qv;
    __syncthreads();

    float ts = 0.f, tq = 0.f;
#pragma unroll
    for (int sp = 0; sp < 4; ++sp) {
        ts += red_s[sp * 64 + nloc];
        tq += red_q[sp * 64 + nloc];
    }
    float mu  = ts * (1.f / D);
    float var = tq * (1.f / D) - mu * mu;
    float inv = rsqrtf(var + EPSL);

    if (node < N) {
        float4* hp2 = (float4*)(h + (size_t)node * D + split * 16);
        float4 v;
        v.x = (o0.x - mu) * inv; v.y = (o0.y - mu) * inv;
        v.z = (o0.z - mu) * inv; v.w = (o0.w - mu) * inv; hp2[0] = v;
        v.x = (o1.x - mu) * inv; v.y = (o1.y - mu) * inv;
        v.z = (o1.z - mu) * inv; v.w = (o1.w - mu) * inv; hp2[1] = v;
        v.x = (o2.x - mu) * inv; v.y = (o2.y - mu) * inv;
        v.z = (o2.z - mu) * inv; v.w = (o2.w - mu) * inv; hp2[2] = v;
        v.x = (o3.x - mu) * inv; v.y = (o3.y - mu) * inv;
        v.z = (o3.z - mu) * inv; v.w = (o3.w - mu) * inv; hp2[3] = v;
    }
}

// ---------------- aggregation: h += segment_mean(m[src], dst) ------------------
__global__ __launch_bounds__(256) void k_agg(const float* __restrict__ m,
                                             const int* __restrict__ csr,
                                             const int* __restrict__ off,
                                             const int* __restrict__ cnt,
                                             float* __restrict__ h, int N)
{
    int g = threadIdx.x >> 4;
    int c = threadIdx.x & 15;
    int node = blockIdx.x * 16 + g;
    if (node >= N) return;

    int b  = off[node];
    int e2 = off[node + 1];
    float4 s = {0.f, 0.f, 0.f, 0.f};
    for (int e = b; e < e2; ++e) {
        int sn = csr[e];
        float4 v = ((const float4*)(m + (size_t)sn * D))[c];
        s.x += v.x; s.y += v.y; s.z += v.z; s.w += v.w;
    }
    float dnm = fmaxf((float)cnt[node], 1.f);
    float inv = 1.f / dnm;

    float4* hp = (float4*)(h + (size_t)node * D);
    float4 hv = hp[c];
    hv.x = fmaf(s.x, inv, hv.x);
    hv.y = fmaf(s.y, inv, hv.y);
    hv.z = fmaf(s.z, inv, hv.z);
    hv.w = fmaf(s.w, inv, hv.w);
    hp[c] = hv;
}

extern "C" void kernel_launch(void* const* d_in, const int* in_sizes, int n_in,
                              void* d_out, int out_size, void* d_ws, size_t ws_size,
                              hipStream_t stream)
{
    const float* x  = (const float*)d_in[0];
    const int*   ei = (const int*)d_in[1];
    const float* w0 = (const float*)d_in[2];
    const float* b0 = (const float*)d_in[3];
    const float* w1 = (const float*)d_in[4];
    const float* b1 = (const float*)d_in[5];
    const float* wa = (const float*)d_in[6];
    const float* ba = (const float*)d_in[7];
    const float* wb = (const float*)d_in[8];
    const float* bb = (const float*)d_in[9];

    const int N = in_sizes[0] / D_IN;
    const int E = in_sizes[1] / 2;
    const int L = in_sizes[6] / (D * H);

    const int* src = ei;
    const int* dst = ei + E;

    // workspace layout (256B aligned chunks)
    char* ws = (char*)d_ws;
    size_t o = 0;
    auto carve = [&](size_t bytes) -> char* {
        char* p = ws + o;
        o = (o + bytes + 255) & ~(size_t)255;
        return p;
    };
    float* m    = (float*)carve((size_t)N * D * sizeof(float));
    int*   csr  = (int*)  carve((size_t)E * sizeof(int));
    int*   cnt  = (int*)  carve((size_t)N * sizeof(int));
    int*   fill = (int*)  carve((size_t)N * sizeof(int));
    int*   offp = (int*)  carve((size_t)(N + 1) * sizeof(int));
    int*   bsum = (int*)  carve((size_t)1024 * sizeof(int));
    float* w0t  = (float*)carve((size_t)D * D_IN * sizeof(float));
    float* wat  = (float*)carve((size_t)L * H * D * sizeof(float));

    float* h = (float*)d_out;

    const int nb = (N + TN - 1) / TN;
    const int G1 = (N + 255) / 256;

    k_transpose_w<<<64, 256, 0, stream>>>(w0, wa, w0t, wat, L);
    k_zero<<<(N + 255) / 256, 256, 0, stream>>>(cnt, N);
    k_zero<<<(N + 255) / 256, 256, 0, stream>>>(fill, N);
    k_hist<<<(E + 255) / 256, 256, 0, stream>>>(dst, cnt, E);
    k_scan_blk<<<G1, 256, 0, stream>>>(cnt, offp, bsum, N);
    k_scan_top<<<1, 1024, 0, stream>>>(bsum, G1);
    k_scan_add<<<G1, 256, 0, stream>>>(offp, bsum, N);
    k_fill<<<(E + 255) / 256, 256, 0, stream>>>(src, dst, offp, fill, csr, E);

    k_init<<<nb, 256, 0, stream>>>(x, w0t, b0, w1, b1, h, N);

    for (int l = 0; l < L; ++l) {
        k_mlp<<<nb, 256, 0, stream>>>(h, wat + (size_t)l * H * D,
                                      ba + (size_t)l * H,
                                      wb + (size_t)l * H * D,
                                      bb + (size_t)l * D, m, N);
        k_agg<<<(N + 15) / 16, 256, 0, stream>>>(m, csr, offp, cnt, h, N);
    }
}